// Round 5
// baseline (178.101 us; speedup 1.0000x reference)
//
#include <hip/hip_runtime.h>
#include <stdint.h>

#define Nd 8000
#define Nk 2000
#define FD 32
#define FK 16
#define HD 64
#define NH 8
#define KP 2048
#define LOG2E 1.44269504088896f
#define NSLOPE 0.2f

typedef float f4 __attribute__((ext_vector_type(4)));
typedef short s16x8 __attribute__((ext_vector_type(8)));
typedef unsigned int u32;
typedef unsigned short u16;
typedef unsigned int u4v __attribute__((ext_vector_type(4)));

// ---- workspace layout (bytes), 16B aligned; total ~14.8 MB (exercised in R1-R3) ----
#define WS_WHKT   0            // bf16 [8][64][2048]            4,194,304
#define WS_SK     4194304      // f32 [8][2048] (pre-scaled)       65,536
#define WS_SD     4259840      // f32 [8][8000]                   256,000
#define WS_ADJB   4515840      // u32 [8000][64] bitmask        2,048,000
#define WS_WFT    6563840      // bf16 [64][512]                   65,536
#define WS_HP     6629376      // bf16 [8000][512]              8,192,000
#define WS_HDRONE WS_HP        // f32 [8000][64] OVERLAY: dead before k_attn writes hp
#define WS_FLAG   14821376     // int[2]

__device__ inline float bf2f(u16 v){ return __uint_as_float(((u32)v) << 16); }
__device__ inline u16 f2bf_rne(float f){
  u32 u = __float_as_uint(f);
  u32 r = u + 0x7fffu + ((u >> 16) & 1u);
  return (u16)(r >> 16);
}
__device__ inline float elu1(float x){
  return x > 0.f ? x : (__builtin_amdgcn_exp2f(x * LOG2E) - 1.f);
}
// dtype-agnostic input load: flag selects f32 vs packed-bf16 view of float inputs
__device__ inline float ldin(const void* p, int i, int f32){
  return f32 ? ((const float*)p)[i] : bf2f(((const u16*)p)[i]);
}

// ---------- probe: detect whether float inputs are f32 or bf16 on device ----------
__global__ __launch_bounds__(256) void k_probe(const u16* __restrict__ raw,
                                               int* __restrict__ flag){
  int i0 = blockIdx.x * 256 + threadIdx.x;
  int local = 0;
  for (int i = i0; i < 256000; i += 64 * 256) {
    u32 e = (raw[i] >> 7) & 0xFFu;
    local += (e >= 0xC8u) ? 1 : 0;
  }
  if (local) atomicAdd(&flag[1], local);
}

// ---------- prep: h_dock = elu(raw_dock @ Wpk + bpk) -> output 1 (f32) ----------
__global__ __launch_bounds__(256) void k_dock(const void* __restrict__ rd,
                                              const void* __restrict__ Wpk,
                                              const void* __restrict__ bpk,
                                              float* __restrict__ out_hdock,
                                              const int* __restrict__ flag){
  int f32 = flag[1] > 1000;
  int id = blockIdx.x * 256 + threadIdx.x;  // 2000*64 = 128000 exact
  int k = id >> 6, f = id & 63;
  float acc = ldin(bpk, f, f32);
  #pragma unroll
  for (int j = 0; j < FK; ++j)
    acc += ldin(rd, k * FK + j, f32) * ldin(Wpk, j * HD + f, f32);
  out_hdock[id] = elu1(acc);
}

// ---------- prep: h_drone = elu(raw_drone @ Wpd + bpd) (f32 ws) ----------
__global__ __launch_bounds__(256) void k_drone(const void* __restrict__ rd,
                                               const void* __restrict__ Wpd,
                                               const void* __restrict__ bpd,
                                               float* __restrict__ hdrone,
                                               const int* __restrict__ flag){
  int f32 = flag[1] > 1000;
  int id = blockIdx.x * 256 + threadIdx.x;  // 8000*64 = 512000 exact
  int n = id >> 6, f = id & 63;
  float acc = ldin(bpd, f, f32);
  #pragma unroll
  for (int j = 0; j < FD; ++j)
    acc += ldin(rd, n * FD + j, f32) * ldin(Wpd, j * HD + f, f32);
  hdrone[id] = elu1(acc);
}

// ---------- prep: WhkT[h][f][k] bf16 (k padded->0), sk[h][k] = (Whk@a2)*log2e ----------
// reads h_dock f32 from d_out's second region. LDS ~26.6 KB.
__global__ __launch_bounds__(256) void k_whk(const float* __restrict__ hdock,
                                             const void* __restrict__ Wa,
                                             const void* __restrict__ a2,
                                             u16* __restrict__ whkT,
                                             float* __restrict__ sk,
                                             const int* __restrict__ flag){
  int f32 = flag[1] > 1000;
  int kt = blockIdx.x;  // 0..31 (64 docks each, padded to 2048)
  int h  = blockIdx.y;  // 0..7
  int t = threadIdx.x;
  __shared__ float hs[64 * 68];   // [dock][d] f32, stride 68
  __shared__ u16 ts[64 * 64];     // [f][k] bf16 transpose staging
  __shared__ float part[64 * 4];
  {
    int row = t >> 2, dq = (t & 3) * 16;
    int gk = kt * 64 + row;
    if (gk < Nk) {
      #pragma unroll
      for (int q = 0; q < 4; ++q) {
        f4 x = *(const f4*)(hdock + gk * HD + dq + q * 4);
        hs[row * 68 + dq + q*4+0] = x[0]; hs[row * 68 + dq + q*4+1] = x[1];
        hs[row * 68 + dq + q*4+2] = x[2]; hs[row * 68 + dq + q*4+3] = x[3];
      }
    } else {
      #pragma unroll
      for (int q = 0; q < 16; ++q) hs[row * 68 + dq + q] = 0.f;
    }
  }
  __syncthreads();
  int k = t & 63, fq = t >> 6;   // wave fq handles features fq*16..fq*16+15
  float acc[16];
  #pragma unroll
  for (int j = 0; j < 16; ++j) acc[j] = 0.f;
  for (int d = 0; d < HD; ++d) {
    float hv = hs[k * 68 + d];
    #pragma unroll
    for (int j = 0; j < 16; ++j)
      acc[j] += hv * ldin(Wa, (h * HD + d) * HD + fq * 16 + j, f32);
  }
  float ps = 0.f;
  #pragma unroll
  for (int j = 0; j < 16; ++j) ps += acc[j] * ldin(a2, h * HD + fq * 16 + j, f32);
  part[k * 4 + fq] = ps;
  #pragma unroll
  for (int j = 0; j < 16; ++j)
    ts[(fq * 16 + j) * 64 + k] = f2bf_rne(acc[j]);
  __syncthreads();
  if (t < 64) {
    float s = (part[t*4+0] + part[t*4+1]) + (part[t*4+2] + part[t*4+3]);
    sk[h * KP + kt * 64 + t] = s * LOG2E;
  }
  {
    int f = t >> 2, kq = t & 3;
    u16* dst = whkT + (h * HD + f) * KP + kt * 64 + kq * 16;
    *(u4v*)dst       = *(const u4v*)&ts[f * 64 + kq * 16];
    *(u4v*)(dst + 8) = *(const u4v*)&ts[f * 64 + kq * 16 + 8];
  }
}

// ---------- prep: sd[h][n] = (h_drone[n] . (Wa[h] @ a1[h])) * log2e ----------
__global__ __launch_bounds__(256) void k_sd(const float* __restrict__ hdrone,
                                            const void* __restrict__ Wa,
                                            const void* __restrict__ a1,
                                            float* __restrict__ sd,
                                            const int* __restrict__ flag){
  int f32 = flag[1] > 1000;
  int h = blockIdx.y;
  int t = threadIdx.x;
  __shared__ float wa1[64];
  if (t < 64) {
    float s = 0.f;
    #pragma unroll
    for (int f = 0; f < 64; ++f)
      s += ldin(Wa, (h * HD + t) * HD + f, f32) * ldin(a1, h * HD + f, f32);
    wa1[t] = s;
  }
  __syncthreads();
  int n = blockIdx.x * 256 + t;
  if (n < Nd) {
    float acc = 0.f;
    #pragma unroll
    for (int q = 0; q < 16; ++q) {
      f4 x = *(const f4*)(hdrone + n * HD + q * 4);
      acc += x[0]*wa1[q*4+0] + x[1]*wa1[q*4+1] + x[2]*wa1[q*4+2] + x[3]*wa1[q*4+3];
    }
    sd[h * Nd + n] = acc * LOG2E;
  }
}

// ---------- prep: adj [8000][2000] int32 -> bitmask [8000][64] u32 ----------
__global__ __launch_bounds__(256) void k_adjb(const int* __restrict__ adj,
                                              unsigned long long* __restrict__ adjb){
  int wv = threadIdx.x >> 6, lane = threadIdx.x & 63;
  int n = blockIdx.x * 4 + wv;  // grid 2000 -> 8000 exact
  for (int c = 0; c < 32; ++c) {
    int k = c * 64 + lane;
    int v = (k < Nk) ? adj[n * Nk + k] : 0;
    unsigned long long m = __ballot(v != 0);
    if (lane == 0) adjb[n * 32 + c] = m;
  }
}

// ---------- prep: WfT[j][k] = Wf[k][j] (bf16) ----------
__global__ __launch_bounds__(256) void k_wft(const void* __restrict__ Wf,
                                             u16* __restrict__ wfT,
                                             const int* __restrict__ flag){
  int f32 = flag[1] > 1000;
  int id = blockIdx.x * 256 + threadIdx.x;  // 64*512 = 32768 exact
  int j = id >> 9, k = id & 511;
  wfT[id] = f2bf_rne(ldin(Wf, k * HD + j, f32));
}

// ---------- main: masked softmax(leaky(sd+sk)) @ Whk, fused via MFMA ----------
// Denominator computed IN the MFMA path (ones-column B fragment) -> num/den
// consistent by construction.
__global__ __launch_bounds__(256) void k_attn(const float* __restrict__ sd,
                                              const float* __restrict__ sk,
                                              const u16* __restrict__ whkT,
                                              const u32* __restrict__ adjb,
                                              u16* __restrict__ hp){
  int h = blockIdx.y;
  int nt = blockIdx.x;
  int t = threadIdx.x;
  int w = t >> 6, lane = t & 63;
  int g = lane >> 4, c16 = lane & 15;
  int r0 = nt * 128 + w * 32;

  __shared__ u16 ldsb[4 * 64 * 8];   // [kgroup][feat][e] fragment-contiguous
  __shared__ u16 ldshp[128 * 64];

  float sdv[2];
  int rowA[2];
  #pragma unroll
  for (int m = 0; m < 2; ++m) {
    rowA[m] = r0 + m * 16 + c16;
    sdv[m] = (rowA[m] < Nd) ? sd[h * Nd + rowA[m]] : 0.f;
  }
  f4 acc[2][4];
  f4 accd[2];                        // denominator accumulators (col 0 at c16==0)
  #pragma unroll
  for (int m = 0; m < 2; ++m) {
    accd[m] = (f4){0.f, 0.f, 0.f, 0.f};
    #pragma unroll
    for (int cc = 0; cc < 4; ++cc)
      acc[m][cc] = (f4){0.f, 0.f, 0.f, 0.f};
  }
  // all-ones column 0 of B: lanes with c16==0 carry bf16 1.0 in every k-slot
  s16x8 onesf = (s16x8)(short)((c16 == 0) ? 0x3F80 : 0);

  const u16* wsrc = whkT + (h * HD + lane) * KP + w * 8;  // wave w stages kgroup w

  for (int kb = 0; kb < 64; ++kb) {
    int kbase = kb * 32;
    u4v bv = *(const u4v*)(wsrc + kbase);                 // issued early
    f4 s0 = *(const f4*)(sk + h * KP + kbase + g * 8);
    f4 s1 = *(const f4*)(sk + h * KP + kbase + g * 8 + 4);
    union { s16x8 v; u16 u[8]; } af[2];
    #pragma unroll
    for (int m = 0; m < 2; ++m) {
      u32 aw = (rowA[m] < Nd) ? adjb[rowA[m] * 64 + kb] : 0u;
      u32 ab = (aw >> (g * 8)) & 0xffu;
      #pragma unroll
      for (int e = 0; e < 8; ++e) {
        float x = sdv[m] + (e < 4 ? s0[e] : s1[e - 4]);
        x = x > 0.f ? x : x * NSLOPE;                     // leaky (commutes with log2e)
        float p = __builtin_amdgcn_exp2f(x);
        p = ((ab >> e) & 1u) ? p : 0.f;
        af[m].u[e] = f2bf_rne(p);
      }
    }
    __syncthreads();                                      // prev-iter LDS reads done
    *(u4v*)&ldsb[(w * 64 + lane) * 8] = bv;
    __syncthreads();                                      // tile visible
    s16x8 bfr[4];
    #pragma unroll
    for (int cc = 0; cc < 4; ++cc)
      bfr[cc] = *(const s16x8*)&ldsb[(g * 64 + cc * 16 + c16) * 8];
    #pragma unroll
    for (int m = 0; m < 2; ++m) {
      accd[m] = __builtin_amdgcn_mfma_f32_16x16x32_bf16(af[m].v, onesf, accd[m], 0, 0, 0);
      #pragma unroll
      for (int cc = 0; cc < 4; ++cc)
        acc[m][cc] = __builtin_amdgcn_mfma_f32_16x16x32_bf16(af[m].v, bfr[cc], acc[m][cc], 0, 0, 0);
    }
  }

  // epilogue: den for row (g*4+j) lives in lane (g*16, c16=0), reg j -> broadcast
  #pragma unroll
  for (int m = 0; m < 2; ++m) {
    #pragma unroll
    for (int j = 0; j < 4; ++j) {
      float den = __shfl(accd[m][j], lane & 48);
      int row = r0 + m * 16 + g * 4 + j;
      float linv = (row < Nd && den > 0.f) ? 1.f / den : 0.f;
      #pragma unroll
      for (int cc = 0; cc < 4; ++cc) {
        float o = acc[m][cc][j] * linv;
        ldshp[(w * 32 + m * 16 + g * 4 + j) * 64 + cc * 16 + c16] = f2bf_rne(elu1(o));
      }
    }
  }
  __syncthreads();
  {
    int r = t >> 1, half = t & 1;
    int row = nt * 128 + r;
    if (row < Nd) {
      u16* dst = hp + row * 512 + h * 64 + half * 32;
      const u16* src = ldshp + r * 64 + half * 32;
      *(u4v*)(dst)      = *(const u4v*)(src);
      *(u4v*)(dst + 8)  = *(const u4v*)(src + 8);
      *(u4v*)(dst + 16) = *(const u4v*)(src + 16);
      *(u4v*)(dst + 24) = *(const u4v*)(src + 24);
    }
  }
}

// ---------- epilogue: out_drone = hp @ Wf + bf (MFMA), f32 output ----------
__global__ __launch_bounds__(256) void k_out(const u16* __restrict__ hp,
                                             const u16* __restrict__ wfT,
                                             const void* __restrict__ bfv,
                                             float* __restrict__ out,
                                             const int* __restrict__ flag){
  int f32 = flag[1] > 1000;
  int t = threadIdx.x;
  int w = t >> 6, lane = t & 63;
  int g = lane >> 4, c16 = lane & 15;
  int r0 = blockIdx.x * 64 + w * 16;  // grid 125 -> 8000 exact
  f4 acc[4];
  #pragma unroll
  for (int cc = 0; cc < 4; ++cc) acc[cc] = (f4){0.f, 0.f, 0.f, 0.f};
  const u16* ap = hp + (r0 + c16) * 512 + g * 8;
  for (int kb = 0; kb < 16; ++kb) {
    s16x8 a = *(const s16x8*)(ap + kb * 32);
    #pragma unroll
    for (int cc = 0; cc < 4; ++cc) {
      s16x8 b = *(const s16x8*)(wfT + (cc * 16 + c16) * 512 + kb * 32 + g * 8);
      acc[cc] = __builtin_amdgcn_mfma_f32_16x16x32_bf16(a, b, acc[cc], 0, 0, 0);
    }
  }
  #pragma unroll
  for (int cc = 0; cc < 4; ++cc) {
    float bias = ldin(bfv, cc * 16 + c16, f32);
    #pragma unroll
    for (int j = 0; j < 4; ++j) {
      int row = r0 + g * 4 + j;
      out[row * HD + cc * 16 + c16] = acc[cc][j] + bias;
    }
  }
}

extern "C" void kernel_launch(void* const* d_in, const int* in_sizes, int n_in,
                              void* d_out, int out_size, void* d_ws, size_t ws_size,
                              hipStream_t stream) {
  const void* raw_drone = d_in[0];
  const void* raw_dock  = d_in[1];
  const int* adj        = (const int*)d_in[2];
  const void* Wpd = d_in[3];
  const void* bpd = d_in[4];
  const void* Wpk = d_in[5];
  const void* bpk = d_in[6];
  const void* Wa  = d_in[7];
  const void* a1  = d_in[8];
  const void* a2  = d_in[9];
  const void* Wf  = d_in[10];
  const void* bfb = d_in[11];
  float* out = (float*)d_out;            // f32 outputs (reference dtype)
  float* out_hdock = out + Nd * HD;      // output 1 region

  char* ws = (char*)d_ws;
  u16*   whkT   = (u16*)(ws + WS_WHKT);
  float* skv    = (float*)(ws + WS_SK);
  float* sdv    = (float*)(ws + WS_SD);
  u32*   adjb   = (u32*)(ws + WS_ADJB);
  u16*   wfT    = (u16*)(ws + WS_WFT);
  u16*   hp     = (u16*)(ws + WS_HP);
  float* hdrone = (float*)(ws + WS_HDRONE);  // overlays hp (dead before k_attn)
  int*   flag   = (int*)(ws + WS_FLAG);

  hipMemsetAsync(flag, 0, 8, stream);
  k_probe<<<64, 256, 0, stream>>>((const u16*)raw_drone, flag);
  k_dock <<<500, 256, 0, stream>>>(raw_dock, Wpk, bpk, out_hdock, flag);
  k_drone<<<2000, 256, 0, stream>>>(raw_drone, Wpd, bpd, hdrone, flag);
  k_whk  <<<dim3(32, 8), 256, 0, stream>>>(out_hdock, Wa, a2, whkT, skv, flag);
  k_sd   <<<dim3(32, 8), 256, 0, stream>>>(hdrone, Wa, a1, sdv, flag);
  k_adjb <<<2000, 256, 0, stream>>>(adj, (unsigned long long*)adjb);
  k_wft  <<<128, 256, 0, stream>>>(Wf, wfT, flag);
  k_attn <<<dim3(63, 8), 256, 0, stream>>>(sdv, skv, whkT, adjb, hp);
  k_out  <<<125, 256, 0, stream>>>(hp, wfT, bfb, out, flag);
}

// Round 6
// 113.679 us; speedup vs baseline: 1.5667x; 1.5667x over previous
//
#include <hip/hip_runtime.h>
#include <stdint.h>

#define Nd 8000
#define Nk 2000
#define FD 32
#define FK 16
#define HD 64
#define NH 8
#define KP 2048
#define NKB 64   // KP/32
#define LOG2E 1.44269504088896f
#define NSLOPE 0.2f

typedef float f4 __attribute__((ext_vector_type(4)));
typedef short s16x8 __attribute__((ext_vector_type(8)));
typedef unsigned int u32;
typedef unsigned short u16;
typedef unsigned int u4v __attribute__((ext_vector_type(4)));

// ---- workspace layout (bytes), 16B aligned; total ~12.7 MB ----
#define WS_WHKB   0          // bf16 [8][64 kb][4 cc][64 lane][8 e] = 2 MB
#define WS_SK     2097152    // f32 [8][2048] (pre-scaled by log2e)
#define WS_SD     2162688    // f32 [8][8000] (pre-scaled by log2e)
#define WS_ADJB   2418688    // u32 [8000][64] bitmask (bit = k%32, word = k/32)
#define WS_WFT    4466688    // bf16 [64 j][512 k]
#define WS_HP     4532224    // bf16 [8000][512]

__device__ inline u16 f2bf_rne(float f){
  u32 u = __float_as_uint(f);
  u32 r = u + 0x7fffu + ((u >> 16) & 1u);
  return (u16)(r >> 16);
}
__device__ inline float elu1(float x){
  return x > 0.f ? x : (__builtin_amdgcn_exp2f(x * LOG2E) - 1.f);
}

// ---------- fused prep: h_dock (-> output 1), WhkB bf16, sk; h==1 also WfT ----------
// grid (64 kt x 8 h), 256 thr; block covers docks kt*32..+31 (k-padded to 2048)
__global__ __launch_bounds__(256) void k_whk(const float* __restrict__ rdock,
                                             const float* __restrict__ Wpk,
                                             const float* __restrict__ bpk,
                                             const float* __restrict__ Wa,
                                             const float* __restrict__ a2,
                                             const float* __restrict__ Wf,
                                             float* __restrict__ out_hdock,
                                             u16* __restrict__ whkB,
                                             float* __restrict__ sk,
                                             u16* __restrict__ wfT){
  int kt = blockIdx.x, h = blockIdx.y;
  int t = threadIdx.x;
  __shared__ float hs[32 * 65];
  __shared__ float part[32 * 8];
  __shared__ u16 ts[64 * 32];   // [f][k_local]

  // side-job: h==1 blocks build WfT (64 blocks x 256 thr x 2 elems = 32768)
  if (h == 1) {
    int id = kt * 256 + t;
    #pragma unroll
    for (int i = 0; i < 2; ++i) {
      int idx = id * 2 + i;              // idx = j*512 + k
      int j = idx >> 9, k = idx & 511;
      wfT[idx] = f2bf_rne(Wf[k * HD + j]);
    }
  }
  // phase A: h_dock rows (8 elems/thread, 16-FMA each)
  {
    int r = t >> 3, f0 = (t & 7) * 8;
    int gk = kt * 32 + r;
    float v[8];
    if (gk < Nk) {
      #pragma unroll
      for (int q = 0; q < 8; ++q) v[q] = bpk[f0 + q];
      for (int j = 0; j < FK; ++j) {
        float x = rdock[gk * FK + j];
        #pragma unroll
        for (int q = 0; q < 8; ++q) v[q] += x * Wpk[j * HD + f0 + q];
      }
      #pragma unroll
      for (int q = 0; q < 8; ++q) v[q] = elu1(v[q]);
      if (h == 0) {
        #pragma unroll
        for (int q = 0; q < 8; ++q) out_hdock[gk * HD + f0 + q] = v[q];
      }
    } else {
      #pragma unroll
      for (int q = 0; q < 8; ++q) v[q] = 0.f;
    }
    #pragma unroll
    for (int q = 0; q < 8; ++q) hs[r * 65 + f0 + q] = v[q];
  }
  __syncthreads();
  // phase B: Whk tile (thread: dock kl, features fq*8..+7), a2 partials
  {
    int kl = t & 31, fq = t >> 5;
    float acc[8];
    #pragma unroll
    for (int j = 0; j < 8; ++j) acc[j] = 0.f;
    for (int d = 0; d < HD; ++d) {
      float hv = hs[kl * 65 + d];
      const float* wr = Wa + (h * HD + d) * HD + fq * 8;
      #pragma unroll
      for (int j = 0; j < 8; ++j) acc[j] += hv * wr[j];
    }
    float ps = 0.f;
    #pragma unroll
    for (int j = 0; j < 8; ++j) ps += acc[j] * a2[h * HD + fq * 8 + j];
    part[kl * 8 + fq] = ps;
    #pragma unroll
    for (int j = 0; j < 8; ++j)
      ts[(fq * 8 + j) * 32 + kl] = f2bf_rne(acc[j]);
  }
  __syncthreads();
  // phase C: sk + fragment-ordered WhkB write
  if (t < 32) {
    float s = 0.f;
    #pragma unroll
    for (int q = 0; q < 8; ++q) s += part[t * 8 + q];
    sk[h * KP + kt * 32 + t] = s * LOG2E;
  }
  {
    int cc = t >> 6, lane = t & 63, g = (t >> 4) & 3, c16 = t & 15;
    int f = cc * 16 + c16;
    u4v val = *(const u4v*)&ts[f * 32 + g * 8];
    *(u4v*)(whkB + (((h * NKB + kt) * 4 + cc) * 64 + lane) * 8) = val;
  }
}

// ---------- fused prep: sd[h][n] = (elu(raw_drone@Wpd+bpd) . (Wa_h@a1_h)) * log2e ----------
__global__ __launch_bounds__(256) void k_dsd(const float* __restrict__ rdrone,
                                             const float* __restrict__ Wpd,
                                             const float* __restrict__ bpd,
                                             const float* __restrict__ Wa,
                                             const float* __restrict__ a1,
                                             float* __restrict__ sd){
  __shared__ float wa1[NH * HD];
  int t = threadIdx.x;
  #pragma unroll
  for (int i = 0; i < 2; ++i) {
    int idx = t + i * 256;
    int h = idx >> 6, d = idx & 63;
    float s = 0.f;
    for (int f = 0; f < HD; ++f) s += Wa[(h * HD + d) * HD + f] * a1[h * HD + f];
    wa1[idx] = s;
  }
  __syncthreads();
  int r4 = t >> 6, d = t & 63;
  for (int rr = 0; rr < 4; ++rr) {
    int n = blockIdx.x * 16 + r4 * 4 + rr;   // 500*16 = 8000 exact
    float acc = bpd[d];
    for (int j = 0; j < FD; ++j) acc += rdrone[n * FD + j] * Wpd[j * HD + d];
    float hd = elu1(acc);
    #pragma unroll
    for (int h = 0; h < NH; ++h) {
      float v = hd * wa1[h * HD + d];
      v += __shfl_xor(v, 1);  v += __shfl_xor(v, 2);  v += __shfl_xor(v, 4);
      v += __shfl_xor(v, 8);  v += __shfl_xor(v, 16); v += __shfl_xor(v, 32);
      if (d == 0) sd[h * Nd + n] = v * LOG2E;
    }
  }
}

// ---------- prep: adj [8000][2000] int32 -> bitmask [8000][64] u32 ----------
__global__ __launch_bounds__(256) void k_adjb(const int* __restrict__ adj,
                                              unsigned long long* __restrict__ adjb){
  int wv = threadIdx.x >> 6, lane = threadIdx.x & 63;
  int n = blockIdx.x * 4 + wv;  // grid 2000 -> 8000 exact
  for (int c = 0; c < 32; ++c) {
    int k = c * 64 + lane;
    int v = (k < Nk) ? adj[n * Nk + k] : 0;
    unsigned long long m = __ballot(v != 0);
    if (lane == 0) adjb[n * 32 + c] = m;
  }
}

// ---------- main: masked softmax(leaky(sd+sk)) @ Whk via MFMA, barrier-free loop ----------
// grid (63 x 8), 256 thr; wave w owns rows nt*128+w*32..+31 (2 A-frags)
__global__ __launch_bounds__(256) void k_attn(const float* __restrict__ sd,
                                              const float* __restrict__ sk,
                                              const u16* __restrict__ whkB,
                                              const u32* __restrict__ adjb,
                                              u16* __restrict__ hp){
  int h = blockIdx.y, nt = blockIdx.x;
  int t = threadIdx.x;
  int w = t >> 6, lane = t & 63, g = lane >> 4, c16 = lane & 15;
  int r0 = nt * 128 + w * 32;
  __shared__ u16 ldshp[128 * 64];

  int rowA[2]; float sdv[2];
  #pragma unroll
  for (int m = 0; m < 2; ++m) {
    rowA[m] = min(r0 + m * 16 + c16, Nd - 1);  // clamp: dead rows compute, never store
    sdv[m] = sd[h * Nd + rowA[m]];
  }
  f4 acc[2][4], accd[2];
  #pragma unroll
  for (int m = 0; m < 2; ++m) {
    accd[m] = (f4){0.f, 0.f, 0.f, 0.f};
    #pragma unroll
    for (int cc = 0; cc < 4; ++cc) acc[m][cc] = (f4){0.f, 0.f, 0.f, 0.f};
  }
  s16x8 onesf = (s16x8)(short)((c16 == 0) ? 0x3F80 : 0);

  const u16* bb = whkB + h * (NKB * 4 * 64 * 8);
  const float* skh = sk + h * KP;
  const u32* ap0 = adjb + rowA[0] * 64;
  const u32* ap1 = adjb + rowA[1] * 64;

  for (int kb4 = 0; kb4 < 16; ++kb4) {
    u4v aw0 = *(const u4v*)(ap0 + kb4 * 4);
    u4v aw1 = *(const u4v*)(ap1 + kb4 * 4);
    #pragma unroll
    for (int u = 0; u < 4; ++u) {
      int kb = kb4 * 4 + u;
      const float* sp = skh + kb * 32 + g * 8;
      f4 s0 = *(const f4*)sp;
      f4 s1 = *(const f4*)(sp + 4);
      const u16* bp = bb + kb * 2048 + lane * 8;
      s16x8 b0 = *(const s16x8*)(bp);
      s16x8 b1 = *(const s16x8*)(bp + 512);
      s16x8 b2 = *(const s16x8*)(bp + 1024);
      s16x8 b3 = *(const s16x8*)(bp + 1536);
      u32 awm0 = aw0[u], awm1 = aw1[u];
      union { s16x8 v; u32 d[4]; } af[2];
      #pragma unroll
      for (int m = 0; m < 2; ++m) {
        u32 ab = ((m ? awm1 : awm0) >> (g * 8)) & 0xffu;
        float p[8];
        #pragma unroll
        for (int e = 0; e < 8; ++e) {
          float x = sdv[m] + (e < 4 ? s0[e] : s1[e - 4]);
          x = fmaxf(x, x * NSLOPE);                  // leaky (log2e pre-folded)
          float pe = __builtin_amdgcn_exp2f(x);
          p[e] = (ab & (1u << e)) ? pe : 0.f;
        }
        #pragma unroll
        for (int jj = 0; jj < 4; ++jj)
          asm("v_cvt_pk_bf16_f32 %0, %1, %2"
              : "=v"(af[m].d[jj]) : "v"(p[2 * jj]), "v"(p[2 * jj + 1]));
      }
      #pragma unroll
      for (int m = 0; m < 2; ++m) {
        accd[m]   = __builtin_amdgcn_mfma_f32_16x16x32_bf16(af[m].v, onesf, accd[m], 0, 0, 0);
        acc[m][0] = __builtin_amdgcn_mfma_f32_16x16x32_bf16(af[m].v, b0, acc[m][0], 0, 0, 0);
        acc[m][1] = __builtin_amdgcn_mfma_f32_16x16x32_bf16(af[m].v, b1, acc[m][1], 0, 0, 0);
        acc[m][2] = __builtin_amdgcn_mfma_f32_16x16x32_bf16(af[m].v, b2, acc[m][2], 0, 0, 0);
        acc[m][3] = __builtin_amdgcn_mfma_f32_16x16x32_bf16(af[m].v, b3, acc[m][3], 0, 0, 0);
      }
    }
  }

  // epilogue: den broadcast from col-0 lanes, normalize+elu, stage hp
  #pragma unroll
  for (int m = 0; m < 2; ++m) {
    #pragma unroll
    for (int j = 0; j < 4; ++j) {
      float den = __shfl(accd[m][j], lane & 48);
      int row = r0 + m * 16 + g * 4 + j;
      float linv = (row < Nd && den > 0.f) ? 1.f / den : 0.f;
      #pragma unroll
      for (int cc = 0; cc < 4; ++cc) {
        float o = acc[m][cc][j] * linv;
        ldshp[(w * 32 + m * 16 + g * 4 + j) * 64 + cc * 16 + c16] = f2bf_rne(elu1(o));
      }
    }
  }
  __syncthreads();
  {
    int r = t >> 1, half = t & 1;
    int row = nt * 128 + r;
    if (row < Nd) {
      u16* dst = hp + row * 512 + h * 64 + half * 32;
      const u16* src = ldshp + r * 64 + half * 32;
      *(u4v*)(dst)      = *(const u4v*)(src);
      *(u4v*)(dst + 8)  = *(const u4v*)(src + 8);
      *(u4v*)(dst + 16) = *(const u4v*)(src + 16);
      *(u4v*)(dst + 24) = *(const u4v*)(src + 24);
    }
  }
}

// ---------- epilogue: out_drone = hp @ Wf + bf (MFMA), f32 output ----------
__global__ __launch_bounds__(256) void k_out(const u16* __restrict__ hp,
                                             const u16* __restrict__ wfT,
                                             const float* __restrict__ bfv,
                                             float* __restrict__ out){
  int t = threadIdx.x;
  int w = t >> 6, lane = t & 63, g = lane >> 4, c16 = lane & 15;
  int r0 = blockIdx.x * 64 + w * 16;  // grid 125 -> 8000 exact
  f4 acc[4];
  #pragma unroll
  for (int cc = 0; cc < 4; ++cc) acc[cc] = (f4){0.f, 0.f, 0.f, 0.f};
  const u16* ap = hp + (r0 + c16) * 512 + g * 8;
  for (int kb = 0; kb < 16; ++kb) {
    s16x8 a = *(const s16x8*)(ap + kb * 32);
    #pragma unroll
    for (int cc = 0; cc < 4; ++cc) {
      s16x8 b = *(const s16x8*)(wfT + (cc * 16 + c16) * 512 + kb * 32 + g * 8);
      acc[cc] = __builtin_amdgcn_mfma_f32_16x16x32_bf16(a, b, acc[cc], 0, 0, 0);
    }
  }
  #pragma unroll
  for (int cc = 0; cc < 4; ++cc) {
    float bias = bfv[cc * 16 + c16];
    #pragma unroll
    for (int j = 0; j < 4; ++j) {
      int row = r0 + g * 4 + j;
      out[row * HD + cc * 16 + c16] = acc[cc][j] + bias;
    }
  }
}

extern "C" void kernel_launch(void* const* d_in, const int* in_sizes, int n_in,
                              void* d_out, int out_size, void* d_ws, size_t ws_size,
                              hipStream_t stream) {
  const float* raw_drone = (const float*)d_in[0];
  const float* raw_dock  = (const float*)d_in[1];
  const int*   adj       = (const int*)d_in[2];
  const float* Wpd = (const float*)d_in[3];
  const float* bpd = (const float*)d_in[4];
  const float* Wpk = (const float*)d_in[5];
  const float* bpk = (const float*)d_in[6];
  const float* Wa  = (const float*)d_in[7];
  const float* a1  = (const float*)d_in[8];
  const float* a2  = (const float*)d_in[9];
  const float* Wf  = (const float*)d_in[10];
  const float* bfb = (const float*)d_in[11];
  float* out = (float*)d_out;
  float* out_hdock = out + Nd * HD;

  char* ws = (char*)d_ws;
  u16*   whkB = (u16*)(ws + WS_WHKB);
  float* skv  = (float*)(ws + WS_SK);
  float* sdv  = (float*)(ws + WS_SD);
  u32*   adjb = (u32*)(ws + WS_ADJB);
  u16*   wfT  = (u16*)(ws + WS_WFT);
  u16*   hp   = (u16*)(ws + WS_HP);

  k_whk <<<dim3(64, 8), 256, 0, stream>>>(raw_dock, Wpk, bpk, Wa, a2, Wf,
                                          out_hdock, whkB, skv, wfT);
  k_dsd <<<500, 256, 0, stream>>>(raw_drone, Wpd, bpd, Wa, a1, sdv);
  k_adjb<<<2000, 256, 0, stream>>>(adj, (unsigned long long*)adjb);
  k_attn<<<dim3(63, 8), 256, 0, stream>>>(sdv, skv, whkB, adjb, hp);
  k_out <<<125, 256, 0, stream>>>(hp, wfT, bfb, out);
}